// Round 1
// baseline (95.284 us; speedup 1.0000x reference)
//
#include <hip/hip_runtime.h>

#define N_BINS 15

// fl(1/15) as fp32 — matches jnp.linspace's step
#define INV15 0.066666670143604278564453125f

__global__ __launch_bounds__(256) void ece_accum(
    const float* __restrict__ logits,
    const int* __restrict__ labels,
    int N,
    float* __restrict__ g_conf,
    unsigned* __restrict__ g_cnt,
    unsigned* __restrict__ g_acc) {

  __shared__ float    s_conf[N_BINS];
  __shared__ unsigned s_pk[N_BINS];   // (count << 16) | acc_sum

  const int tid = threadIdx.x;
  if (tid < N_BINS) { s_conf[tid] = 0.0f; s_pk[tid] = 0u; }
  __syncthreads();

  const int stride = gridDim.x * blockDim.x;
  for (int i = blockIdx.x * blockDim.x + tid; i < N; i += stride) {
    // Row of 10 f32 logits + 10 i32 labels, 8B-aligned -> 5x float2 / 5x int2
    const float2* lp = reinterpret_cast<const float2*>(logits + (size_t)i * 10);
    const int2*   bp = reinterpret_cast<const int2*>(labels + (size_t)i * 10);
    float2 l0 = lp[0], l1 = lp[1], l2 = lp[2], l3 = lp[3], l4 = lp[4];
    int2   b0 = bp[0], b1 = bp[1], b2 = bp[2], b3 = bp[3], b4 = bp[4];

    float lg[10] = {l0.x, l0.y, l1.x, l1.y, l2.x, l2.y, l3.x, l3.y, l4.x, l4.y};
    int   lb[10] = {b0.x, b0.y, b1.x, b1.y, b2.x, b2.y, b3.x, b3.y, b4.x, b4.y};

    float mx   = lg[0];
    int   pred = (lg[0] >= 0.0f) ? 0 : -1;  // sigmoid(x) >= 0.5  <=>  x >= 0
    int   best = lb[0];
    int   lidx = 0;
#pragma unroll
    for (int j = 1; j < 10; ++j) {
      mx = fmaxf(mx, lg[j]);
      if (pred < 0 && lg[j] >= 0.0f) pred = j;     // first index of mask-max
      if (lb[j] > best) { best = lb[j]; lidx = j; } // first occurrence of max
    }
    if (pred < 0) pred = 0;  // all-zero mask -> argmax returns 0

    const float conf = 1.0f / (1.0f + __expf(-mx));  // = max(sigmoid(logits))
    const unsigned acc = (pred == lidx) ? 1u : 0u;

    // smallest b with conf <= (b+1)*INV15; previous-b failure gives conf > lower
    int bin = N_BINS - 1;
#pragma unroll
    for (int b = N_BINS - 2; b >= 0; --b) {
      if (conf <= (float)(b + 1) * INV15) bin = b;
    }

    atomicAdd(&s_conf[bin], conf);
    atomicAdd(&s_pk[bin], (1u << 16) | acc);
  }
  __syncthreads();

  if (tid < N_BINS) {
    atomicAdd(&g_conf[tid], s_conf[tid]);
    atomicAdd(&g_cnt[tid], s_pk[tid] >> 16);
    atomicAdd(&g_acc[tid], s_pk[tid] & 0xFFFFu);
  }
}

__global__ void ece_final(const float* __restrict__ g_conf,
                          const unsigned* __restrict__ g_cnt,
                          const unsigned* __restrict__ g_acc,
                          float* __restrict__ out, int N) {
  if (blockIdx.x == 0 && threadIdx.x == 0) {
    float ece = 0.0f;
    for (int b = 0; b < N_BINS; ++b) {
      const float cnt = (float)g_cnt[b];
      if (cnt > 0.0f) {
        const float safe = fmaxf(cnt, 1.0f);
        const float gap  = fabsf(g_conf[b] / safe - (float)g_acc[b] / safe);
        ece += gap * (cnt / (float)N);
      }
    }
    out[0] = ece;
  }
}

extern "C" void kernel_launch(void* const* d_in, const int* in_sizes, int n_in,
                              void* d_out, int out_size, void* d_ws, size_t ws_size,
                              hipStream_t stream) {
  const float* logits = (const float*)d_in[0];
  const int*   labels = (const int*)d_in[1];
  const int N = in_sizes[0] / 10;  // 4,000,000

  // ws layout: float g_conf[15] | unsigned g_cnt[15] | unsigned g_acc[15]
  float*    g_conf = (float*)d_ws;
  unsigned* g_cnt  = (unsigned*)((char*)d_ws + N_BINS * sizeof(float));
  unsigned* g_acc  = (unsigned*)((char*)d_ws + 2 * N_BINS * sizeof(float));

  hipMemsetAsync(d_ws, 0, 3 * N_BINS * sizeof(float), stream);

  const int block = 256;
  const int grid  = 2048;  // ~8 samples/thread grid-stride; 8 blocks/CU
  ece_accum<<<grid, block, 0, stream>>>(logits, labels, N, g_conf, g_cnt, g_acc);
  ece_final<<<1, 64, 0, stream>>>(g_conf, g_cnt, g_acc, (float*)d_out, N);
}